// Round 1
// baseline (1307.732 us; speedup 1.0000x reference)
//
#include <hip/hip_runtime.h>

typedef unsigned short u16;
typedef __attribute__((ext_vector_type(8))) __bf16 bf16x8;
typedef __attribute__((ext_vector_type(4))) float f32x4;

__device__ __forceinline__ u16 f2bf(float f) {
  union { float f; unsigned u; } v; v.f = f;
  unsigned r = v.u + 0x7fffu + ((v.u >> 16) & 1u);
  return (u16)(r >> 16);
}

__device__ __forceinline__ void gld16(const void* g, const void* l) {
  __builtin_amdgcn_global_load_lds((const __attribute__((address_space(1))) void*)g,
                                   (__attribute__((address_space(3))) void*)l, 16, 0, 0);
}

// raw barrier (no vmcnt drain!) with compiler memory fences
#define BARX() do { asm volatile("" ::: "memory"); __builtin_amdgcn_s_barrier(); \
                    asm volatile("" ::: "memory"); } while (0)
// ds-read drain + scheduler fence (rule #18: stop MFMA hoisting past the wait)
#define LGKM0() do { asm volatile("s_waitcnt lgkmcnt(0)" ::: "memory"); \
                     __builtin_amdgcn_sched_barrier(0); } while (0)

// ---------------- merged small prep ----------------
__global__ __launch_bounds__(256) void k_prep_small(
    const float* w1, const float* rw,
    const float* g1, const float* b1, const float* m1, const float* v1,
    const float* g2, const float* b2, const float* m2, const float* v2,
    u16* w1b, u16* cwt,
    float* scale1, float* shift1, float* scale2, float* shift2, float* cbf)
{
  int i = blockIdx.x * 256 + threadIdx.x;
  if (i < 32768) { w1b[i] = f2bf(w1[i]); return; }
  i -= 32768;
  if (i < 655360) {
    int n = i >> 10, c = i & 1023;
    cwt[i] = (n < 600) ? f2bf(rw[n * 1025 + c]) : (u16)0;
    return;
  }
  i -= 655360;
  if (i < 64) {
    float s = g1[i] * rsqrtf(v1[i] + 1e-5f);
    scale1[i] = s; shift1[i] = b1[i] - m1[i] * s;
  } else if (i < 1088) {
    int c = i - 64;
    float s = g2[c] * rsqrtf(v2[c] + 1e-5f);
    scale2[c] = s; shift2[c] = b2[c] - m2[c] * s;
  } else if (i < 1728) {
    int n = i - 1088;
    cbf[n] = (n < 600) ? rw[n * 1025 + 1024] : 0.f;
  }
}

// w2 (1024,1280,3,3) OIHW -> w2t[dy][o][dx*1280+ci] bf16
__global__ __launch_bounds__(256) void k_prep_w2(const float* w2, u16* w2t) {
  __shared__ float buf[11520];
  int o = blockIdx.x;
  const float* src = w2 + (size_t)o * 11520;
  for (int i = threadIdx.x; i < 11520; i += 256) buf[i] = src[i];
  __syncthreads();
  for (int t = 0; t < 9; ++t) {
    int dy = t / 3, dx = t - dy * 3;
    u16* dst = w2t + ((size_t)dy * 1024 + o) * 3840 + dx * 1280;
    for (int ci = threadIdx.x; ci < 1280; ci += 256) dst[ci] = f2bf(buf[ci * 9 + t]);
  }
}

// feat0 NCHW (64,1024,19,19) -> cat[b][1+h][1+w][256+c] bf16 (NHWC, padded 21x21)
__global__ __launch_bounds__(256) void k_feat0(const float* feat0, u16* cat) {
  __shared__ float tile[32][33];
  int b = blockIdx.z, c0 = blockIdx.y * 32, p0 = blockIdx.x * 32;
  int tid = threadIdx.x;
  int lo = tid & 31, hi = tid >> 5;
#pragma unroll
  for (int pass = 0; pass < 4; ++pass) {
    int cl = pass * 8 + hi;
    int p = p0 + lo;
    tile[cl][lo] = (p < 361) ? feat0[((size_t)(b * 1024 + c0 + cl)) * 361 + p] : 0.f;
  }
  __syncthreads();
#pragma unroll
  for (int pass = 0; pass < 4; ++pass) {
    int pl = pass * 8 + hi;
    int p = p0 + pl;
    if (p < 361) {
      int h = p / 19, w = p - h * 19;
      cat[(((size_t)b * 21 + 1 + h) * 21 + 1 + w) * 1280 + 256 + c0 + lo] = f2bf(tile[lo][pl]);
    }
  }
}

// ---------------- conv1 (1x1, 512->64) + BN + leaky + reorg -> cat ch 0..255 ----------------
__global__ __launch_bounds__(256) void k_conv1(const float* feat1, const u16* w1b,
    const float* scale1, const float* shift1, u16* cat)
{
  __shared__ u16 As[128 * 40];
  __shared__ u16 Bs[64 * 32];
  int tid = threadIdx.x;
  int wave = tid >> 6, lane = tid & 63;
  int wr = wave >> 1, wc = wave & 1;
  int lm = lane & 15, lq = lane >> 4;
  int m0 = blockIdx.x * 128;

  int mLoc = tid & 127, cHalf = tid >> 7;
  int mA = m0 + mLoc;
  int bA = mA / 1444, qA = mA - bA * 1444;
  const float* aG = feat1 + ((size_t)bA * 512) * 1444 + qA;

  const u16* bG = w1b + (tid >> 2) * 512 + (tid & 3) * 8;
  char* BsW = (char*)Bs + wave * 1024;

  f32x4 acc[4][2];
#pragma unroll
  for (int i = 0; i < 4; ++i)
#pragma unroll
    for (int j = 0; j < 2; ++j)
#pragma unroll
      for (int r = 0; r < 4; ++r) acc[i][j][r] = 0.f;

  for (int k0 = 0; k0 < 512; k0 += 32) {
    gld16(bG + k0, BsW);
#pragma unroll
    for (int pass = 0; pass < 16; ++pass) {
      int c = pass * 2 + cHalf;
      As[mLoc * 40 + c] = f2bf(aG[(size_t)(k0 + c) * 1444]);
    }
    __syncthreads();
    bf16x8 aF[4], bF[2];
#pragma unroll
    for (int i = 0; i < 4; ++i)
      aF[i] = *(const bf16x8*)(As + (wr * 64 + i * 16 + lm) * 40 + lq * 8);
#pragma unroll
    for (int j = 0; j < 2; ++j)
      bF[j] = *(const bf16x8*)(Bs + (wc * 32 + j * 16 + lm) * 32 + lq * 8);
#pragma unroll
    for (int i = 0; i < 4; ++i)
#pragma unroll
      for (int j = 0; j < 2; ++j)
        acc[i][j] = __builtin_amdgcn_mfma_f32_16x16x32_bf16(aF[i], bF[j], acc[i][j], 0, 0, 0);
    __syncthreads();
  }

  int o0 = wc * 32;
  float sc[2], sh[2];
#pragma unroll
  for (int j = 0; j < 2; ++j) {
    int o = o0 + j * 16 + lm;
    sc[j] = scale1[o]; sh[j] = shift1[o];
  }
#pragma unroll
  for (int i = 0; i < 4; ++i) {
#pragma unroll
    for (int r = 0; r < 4; ++r) {
      int m = m0 + wr * 64 + i * 16 + lq * 4 + r;
      int b = m / 1444, q = m - b * 1444;
      int yy = q / 38, xx = q - yy * 38;
      size_t base = (((size_t)b * 21 + 1 + (yy >> 1)) * 21 + 1 + (xx >> 1)) * 1280
                  + ((yy & 1) * 2 + (xx & 1)) * 64;
#pragma unroll
      for (int j = 0; j < 2; ++j) {
        float v = acc[i][j][r] * sc[j] + sh[j];
        v = v > 0.f ? v : 0.1f * v;
        cat[base + o0 + j * 16 + lm] = f2bf(v);
      }
    }
  }
}

// ---------------- conv2 (3x3, 1280->1024) + BN + leaky -> pre[m][1024] bf16 ----------------
// Phase-pipelined implicit GEMM (T2+T3+T4+T5):
//   BM=256 BN=128 BK=64, 8 waves (4M x 2N, 64x64/wave), LDS 96 KiB double-buffered.
//   K-tile kt uses buf[kt&1]. 4 phases/tile, one acc quadrant each:
//     p0: read aF01,bF01             -> MFMA (i01 x j01)
//     p1: read aF23                  -> MFMA (i23 x j01)   [A buf retired after p1 end-bar]
//     p2: read bF23, STAGE A(kt+2)   -> MFMA (i23 x j23)   [B buf retired after p2 end-bar]
//     p3: STAGE B(kt+2)              -> MFMA (i01 x j23)
//   Boundary: s_waitcnt vmcnt(6) (kt+2's 6 loads stay in flight) + s_barrier. Never drains
//   except kt==178 tail. LDS XOR swizzle: slot ^= row&7 (16B granule), applied via
//   inverse-swizzled global source (linear gld_lds dest) + swizzled read offsets.
__global__ __launch_bounds__(512) void k_conv2(const u16* cat, const u16* w2t,
    const float* scale2, const float* shift2, u16* pre)
{
  __shared__ __align__(16) u16 As[2][16384];   // [p][row*64 + col], 256x64
  __shared__ __align__(16) u16 Bs[2][8192];    // [p][row*64 + col], 128x64

  int tid = threadIdx.x;
  int wave = tid >> 6, lane = tid & 63;
  int wr = wave >> 1, wc = wave & 1;           // wr 0..3, wc 0..1
  int lm = lane & 15, lq = lane >> 4;
  int n0 = (blockIdx.x & 7) * 128;             // XCD-affine B slice (2.95 MB, L2-resident)
  int m0 = (blockIdx.x >> 3) * 256;

  // ---- staging setup: thread t covers row (r*64 + t>>3), LDS chunk t&7 ----
  int rsub = tid >> 3;                         // 0..63
  int cOff = ((tid & 7) ^ (rsub & 7)) * 8;     // inverse-swizzled source chunk (u16)

  const u16* aBase[4];
#pragma unroll
  for (int r = 0; r < 4; ++r) {
    int m = m0 + r * 64 + rsub; if (m > 23103) m = 23103;
    int b = m / 361, pq = m - b * 361, y = pq / 19, x = pq - y * 19;
    aBase[r] = cat + ((size_t)(b * 21 + y) * 21 + x) * 1280 + cOff;
  }
  const u16* bBase[2];
#pragma unroll
  for (int r = 0; r < 2; ++r)
    bBase[r] = w2t + (size_t)(n0 + r * 64 + rsub) * 3840 + cOff;

  // read-side: row&7 == lm&7 for all fragments (row = base64 + i*16 + lm)
  int c0 = ((0 + lq) ^ (lm & 7)) * 8;          // kk=0 swizzled column
  int c1 = ((4 + lq) ^ (lm & 7)) * 8;          // kk=1 swizzled column
  const u16* aRd = &As[0][(wr * 64 + lm) * 64];
  const u16* bRd = &Bs[0][(wc * 64 + lm) * 64];

  f32x4 acc[4][4];
#pragma unroll
  for (int i = 0; i < 4; ++i)
#pragma unroll
    for (int j = 0; j < 4; ++j)
#pragma unroll
      for (int r = 0; r < 4; ++r) acc[i][j][r] = 0.f;

  // K decomposition: kt = dy*60 + (k0/64), NKT=180
  auto stageA = [&](int p, int aOff) {
#pragma unroll
    for (int r = 0; r < 4; ++r)
      gld16(aBase[r] + aOff, &As[p][r * 4096 + wave * 512]);
  };
  auto stageB = [&](int p, size_t bOff) {
#pragma unroll
    for (int r = 0; r < 2; ++r)
      gld16(bBase[r] + bOff, &Bs[p][r * 4096 + wave * 512]);
  };

  // prologue: tiles 0 and 1 (6 loads each)
  stageA(0, 0);        stageB(0, 0);
  stageA(1, 64);       stageB(1, 64);
  asm volatile("s_waitcnt vmcnt(6)" ::: "memory");   // tile0 landed, tile1 in flight
  __builtin_amdgcn_sched_barrier(0);
  BARX();

  int dyS = 0, koS = 128;                      // K-offset state for tile kt+2

  for (int kt = 0; kt < 180; ++kt) {
    int p = kt & 1;
    const u16* A = aRd + p * 16384;
    const u16* B = bRd + p * 8192;
    bool pf = (kt + 2 < 180);
    int aOff = dyS * 26880 + koS;
    size_t bOff = (size_t)dyS * 3932160 + koS;

    bf16x8 aF[4][2], bF[4][2];

    // ---- phase 0: quad (i01, j01) ----
#pragma unroll
    for (int i = 0; i < 2; ++i) {
      aF[i][0] = *(const bf16x8*)(A + i * 1024 + c0);
      aF[i][1] = *(const bf16x8*)(A + i * 1024 + c1);
    }
#pragma unroll
    for (int j = 0; j < 2; ++j) {
      bF[j][0] = *(const bf16x8*)(B + j * 1024 + c0);
      bF[j][1] = *(const bf16x8*)(B + j * 1024 + c1);
    }
    BARX();
    LGKM0();
    __builtin_amdgcn_s_setprio(1);
#pragma unroll
    for (int i = 0; i < 2; ++i)
#pragma unroll
      for (int j = 0; j < 2; ++j) {
        acc[i][j] = __builtin_amdgcn_mfma_f32_16x16x32_bf16(aF[i][0], bF[j][0], acc[i][j], 0, 0, 0);
        acc[i][j] = __builtin_amdgcn_mfma_f32_16x16x32_bf16(aF[i][1], bF[j][1], acc[i][j], 0, 0, 0);
      }
    __builtin_amdgcn_s_setprio(0);
    BARX();

    // ---- phase 1: quad (i23, j01) ----
#pragma unroll
    for (int i = 2; i < 4; ++i) {
      aF[i][0] = *(const bf16x8*)(A + i * 1024 + c0);
      aF[i][1] = *(const bf16x8*)(A + i * 1024 + c1);
    }
    BARX();
    LGKM0();
    __builtin_amdgcn_s_setprio(1);
#pragma unroll
    for (int i = 2; i < 4; ++i)
#pragma unroll
      for (int j = 0; j < 2; ++j) {
        acc[i][j] = __builtin_amdgcn_mfma_f32_16x16x32_bf16(aF[i][0], bF[j][0], acc[i][j], 0, 0, 0);
        acc[i][j] = __builtin_amdgcn_mfma_f32_16x16x32_bf16(aF[i][1], bF[j][1], acc[i][j], 0, 0, 0);
      }
    __builtin_amdgcn_s_setprio(0);
    BARX();   // A[p] fully read by every wave

    // ---- phase 2: quad (i23, j23); stage A(kt+2) into retired A[p] ----
#pragma unroll
    for (int j = 2; j < 4; ++j) {
      bF[j][0] = *(const bf16x8*)(B + j * 1024 + c0);
      bF[j][1] = *(const bf16x8*)(B + j * 1024 + c1);
    }
    if (pf) stageA(p, aOff);
    BARX();
    LGKM0();
    __builtin_amdgcn_s_setprio(1);
#pragma unroll
    for (int i = 2; i < 4; ++i)
#pragma unroll
      for (int j = 2; j < 4; ++j) {
        acc[i][j] = __builtin_amdgcn_mfma_f32_16x16x32_bf16(aF[i][0], bF[j][0], acc[i][j], 0, 0, 0);
        acc[i][j] = __builtin_amdgcn_mfma_f32_16x16x32_bf16(aF[i][1], bF[j][1], acc[i][j], 0, 0, 0);
      }
    __builtin_amdgcn_s_setprio(0);
    BARX();   // B[p] fully read by every wave

    // ---- phase 3: quad (i01, j23); stage B(kt+2) into retired B[p] ----
    if (pf) stageB(p, bOff);
    __builtin_amdgcn_s_setprio(1);
#pragma unroll
    for (int i = 0; i < 2; ++i)
#pragma unroll
      for (int j = 2; j < 4; ++j) {
        acc[i][j] = __builtin_amdgcn_mfma_f32_16x16x32_bf16(aF[i][0], bF[j][0], acc[i][j], 0, 0, 0);
        acc[i][j] = __builtin_amdgcn_mfma_f32_16x16x32_bf16(aF[i][1], bF[j][1], acc[i][j], 0, 0, 0);
      }
    __builtin_amdgcn_s_setprio(0);

    // advance K state for next kt+2
    koS += 64;
    if (koS == 3840) { koS = 0; ++dyS; }

    // ---- boundary: counted vmcnt, never drain except pipeline tail ----
    if (kt < 179) {
      if (kt == 178) { asm volatile("s_waitcnt vmcnt(0)" ::: "memory"); }
      else           { asm volatile("s_waitcnt vmcnt(6)" ::: "memory"); }
      __builtin_amdgcn_sched_barrier(0);
      BARX();
    }
  }

  // ---- epilogue: BN + leaky -> pre ----
  int nn[4]; float sc[4], sh[4];
#pragma unroll
  for (int j = 0; j < 4; ++j) {
    nn[j] = n0 + wc * 64 + j * 16 + lm;
    sc[j] = scale2[nn[j]]; sh[j] = shift2[nn[j]];
  }
#pragma unroll
  for (int i = 0; i < 4; ++i) {
#pragma unroll
    for (int r = 0; r < 4; ++r) {
      int m = m0 + wr * 64 + i * 16 + lq * 4 + r;
      if (m < 23104) {
        u16* row = pre + (size_t)m * 1024;
#pragma unroll
        for (int j = 0; j < 4; ++j) {
          float v = acc[i][j][r] * sc[j] + sh[j];
          v = v > 0.f ? v : 0.1f * v;
          row[nn[j]] = f2bf(v);
        }
      }
    }
  }
}

// ---------------- einsum: det[cw=600][pix=23104]; A=cwt(640x1024), B=pre(23104x1024) ----
__global__ __launch_bounds__(256) void k_einsum(const u16* pre, const u16* cwt,
    const float* cbf, float* out)
{
  __shared__ u16 As[4096];
  __shared__ u16 Bs[4096];
  int tid = threadIdx.x;
  int wave = tid >> 6, lane = tid & 63;
  int wr = wave >> 1, wc = wave & 1;
  int lm = lane & 15, lq = lane >> 4;
  int m0 = blockIdx.x * 128;
  int n0 = blockIdx.y * 128;

  int r0 = tid >> 2, seg = (tid & 3) * 8;
  const u16* aP0 = cwt + (size_t)(m0 + r0) * 1024 + seg;
  const u16* aP1 = aP0 + (size_t)64 * 1024;
  int q0 = n0 + r0;       if (q0 > 23103) q0 = 23103;
  int q1 = n0 + r0 + 64;  if (q1 > 23103) q1 = 23103;
  const u16* bP0 = pre + (size_t)q0 * 1024 + seg;
  const u16* bP1 = pre + (size_t)q1 * 1024 + seg;

  char* AsW = (char*)As + wave * 1024;
  char* BsW = (char*)Bs + wave * 1024;

  f32x4 acc[4][4];
#pragma unroll
  for (int i = 0; i < 4; ++i)
#pragma unroll
    for (int j = 0; j < 4; ++j)
#pragma unroll
      for (int r = 0; r < 4; ++r) acc[i][j][r] = 0.f;

  for (int k0 = 0; k0 < 1024; k0 += 32) {
    gld16(aP0 + k0, AsW);
    gld16(aP1 + k0, AsW + 4096);
    gld16(bP0 + k0, BsW);
    gld16(bP1 + k0, BsW + 4096);
    __syncthreads();
    bf16x8 aF[4], bF[4];
#pragma unroll
    for (int i = 0; i < 4; ++i)
      aF[i] = *(const bf16x8*)(As + (wr * 64 + i * 16 + lm) * 32 + lq * 8);
#pragma unroll
    for (int j = 0; j < 4; ++j)
      bF[j] = *(const bf16x8*)(Bs + (wc * 64 + j * 16 + lm) * 32 + lq * 8);
#pragma unroll
    for (int i = 0; i < 4; ++i)
#pragma unroll
      for (int j = 0; j < 4; ++j)
        acc[i][j] = __builtin_amdgcn_mfma_f32_16x16x32_bf16(aF[i], bF[j], acc[i][j], 0, 0, 0);
    __syncthreads();
  }

  int pix[4], pb[4], pp[4];
#pragma unroll
  for (int j = 0; j < 4; ++j) {
    pix[j] = n0 + wc * 64 + j * 16 + lm;
    int b = pix[j] / 361;
    pb[j] = b; pp[j] = pix[j] - b * 361;
  }
#pragma unroll
  for (int i = 0; i < 4; ++i) {
#pragma unroll
    for (int r = 0; r < 4; ++r) {
      int cw = m0 + wr * 64 + i * 16 + lq * 4 + r;
      if (cw < 600) {
        float bias = cbf[cw];
#pragma unroll
        for (int j = 0; j < 4; ++j) {
          if (pix[j] < 23104)
            out[(size_t)pb[j] * 216600 + (size_t)cw * 361 + pp[j]] = acc[i][j][r] + bias;
        }
      }
    }
  }
}

// ---------------- launch ----------------

extern "C" void kernel_launch(void* const* d_in, const int* in_sizes, int n_in,
                              void* d_out, int out_size, void* d_ws, size_t ws_size,
                              hipStream_t stream) {
  const float* feat0 = (const float*)d_in[0];
  const float* feat1 = (const float*)d_in[1];
  const float* w1 = (const float*)d_in[2];
  const float* g1 = (const float*)d_in[3];
  const float* b1 = (const float*)d_in[4];
  const float* m1 = (const float*)d_in[5];
  const float* v1 = (const float*)d_in[6];
  const float* w2 = (const float*)d_in[7];
  const float* g2 = (const float*)d_in[8];
  const float* b2 = (const float*)d_in[9];
  const float* m2 = (const float*)d_in[10];
  const float* v2 = (const float*)d_in[11];
  const float* rw = (const float*)d_in[12];
  float* out = (float*)d_out;

  char* ws = (char*)d_ws;
  u16* cat    = (u16*)(ws);                    // 72,253,440 B
  u16* w2t    = (u16*)(ws + 72253440);         // 23,592,960 B
  u16* pre    = (u16*)(ws + 95846400);         // 47,316,992 B
  u16* w1b    = (u16*)(ws + 143163392);
  u16* cwt    = (u16*)(ws + 143228928);
  float* scale1 = (float*)(ws + 144539648);
  float* shift1 = (float*)(ws + 144539904);
  float* scale2 = (float*)(ws + 144540160);
  float* shift2 = (float*)(ws + 144544256);
  float* cbf    = (float*)(ws + 144548352);

  hipMemsetAsync(cat, 0, 72253440, stream);  // zero spatial padding

  k_prep_small<<<2696, 256, 0, stream>>>(w1, rw, g1, b1, m1, v1, g2, b2, m2, v2,
                                         w1b, cwt, scale1, shift1, scale2, shift2, cbf);
  k_prep_w2<<<1024, 256, 0, stream>>>(w2, w2t);
  k_feat0<<<dim3(12, 32, 64), 256, 0, stream>>>(feat0, cat);
  k_conv1<<<722, 256, 0, stream>>>(feat1, w1b, scale1, shift1, cat);
  k_conv2<<<728, 512, 0, stream>>>(cat, w2t, scale2, shift2, pre);
  k_einsum<<<dim3(5, 181), 256, 0, stream>>>(pre, cwt, cbf, out);
}

// Round 2
// 1282.402 us; speedup vs baseline: 1.0198x; 1.0198x over previous
//
#include <hip/hip_runtime.h>

typedef unsigned short u16;
typedef __attribute__((ext_vector_type(8))) __bf16 bf16x8;
typedef __attribute__((ext_vector_type(4))) float f32x4;
typedef __attribute__((ext_vector_type(16))) float f32x16;

__device__ __forceinline__ u16 f2bf(float f) {
  union { float f; unsigned u; } v; v.f = f;
  unsigned r = v.u + 0x7fffu + ((v.u >> 16) & 1u);
  return (u16)(r >> 16);
}

__device__ __forceinline__ void gld16(const void* g, const void* l) {
  __builtin_amdgcn_global_load_lds((const __attribute__((address_space(1))) void*)g,
                                   (__attribute__((address_space(3))) void*)l, 16, 0, 0);
}

// raw barrier (no vmcnt drain) with compiler memory fences
#define BARX() do { asm volatile("" ::: "memory"); __builtin_amdgcn_s_barrier(); \
                    asm volatile("" ::: "memory"); } while (0)
// ds-read drain + scheduler fence (rule #18)
#define LGKM0() do { asm volatile("s_waitcnt lgkmcnt(0)" ::: "memory"); \
                     __builtin_amdgcn_sched_barrier(0); } while (0)

// ---------------- merged small prep ----------------
__global__ __launch_bounds__(256) void k_prep_small(
    const float* w1, const float* rw,
    const float* g1, const float* b1, const float* m1, const float* v1,
    const float* g2, const float* b2, const float* m2, const float* v2,
    u16* w1b, u16* cwt,
    float* scale1, float* shift1, float* scale2, float* shift2, float* cbf)
{
  int i = blockIdx.x * 256 + threadIdx.x;
  if (i < 32768) { w1b[i] = f2bf(w1[i]); return; }
  i -= 32768;
  if (i < 655360) {
    int n = i >> 10, c = i & 1023;
    cwt[i] = (n < 600) ? f2bf(rw[n * 1025 + c]) : (u16)0;
    return;
  }
  i -= 655360;
  if (i < 64) {
    float s = g1[i] * rsqrtf(v1[i] + 1e-5f);
    scale1[i] = s; shift1[i] = b1[i] - m1[i] * s;
  } else if (i < 1088) {
    int c = i - 64;
    float s = g2[c] * rsqrtf(v2[c] + 1e-5f);
    scale2[c] = s; shift2[c] = b2[c] - m2[c] * s;
  } else if (i < 1728) {
    int n = i - 1088;
    cbf[n] = (n < 600) ? rw[n * 1025 + 1024] : 0.f;
  }
}

// w2 (1024,1280,3,3) OIHW -> w2t[dy][o][dx*1280+ci] bf16
__global__ __launch_bounds__(256) void k_prep_w2(const float* w2, u16* w2t) {
  __shared__ float buf[11520];
  int o = blockIdx.x;
  const float* src = w2 + (size_t)o * 11520;
  for (int i = threadIdx.x; i < 11520; i += 256) buf[i] = src[i];
  __syncthreads();
  for (int t = 0; t < 9; ++t) {
    int dy = t / 3, dx = t - dy * 3;
    u16* dst = w2t + ((size_t)dy * 1024 + o) * 3840 + dx * 1280;
    for (int ci = threadIdx.x; ci < 1280; ci += 256) dst[ci] = f2bf(buf[ci * 9 + t]);
  }
}

// feat0 NCHW (64,1024,19,19) -> cat[b][1+h][1+w][256+c] bf16 (NHWC, padded 21x21)
__global__ __launch_bounds__(256) void k_feat0(const float* feat0, u16* cat) {
  __shared__ float tile[32][33];
  int b = blockIdx.z, c0 = blockIdx.y * 32, p0 = blockIdx.x * 32;
  int tid = threadIdx.x;
  int lo = tid & 31, hi = tid >> 5;
#pragma unroll
  for (int pass = 0; pass < 4; ++pass) {
    int cl = pass * 8 + hi;
    int p = p0 + lo;
    tile[cl][lo] = (p < 361) ? feat0[((size_t)(b * 1024 + c0 + cl)) * 361 + p] : 0.f;
  }
  __syncthreads();
#pragma unroll
  for (int pass = 0; pass < 4; ++pass) {
    int pl = pass * 8 + hi;
    int p = p0 + pl;
    if (p < 361) {
      int h = p / 19, w = p - h * 19;
      cat[(((size_t)b * 21 + 1 + h) * 21 + 1 + w) * 1280 + 256 + c0 + lo] = f2bf(tile[lo][pl]);
    }
  }
}

// ---------------- conv1 (1x1, 512->64) + BN + leaky + reorg -> cat ch 0..255 ----------------
__global__ __launch_bounds__(256) void k_conv1(const float* feat1, const u16* w1b,
    const float* scale1, const float* shift1, u16* cat)
{
  __shared__ u16 As[128 * 40];
  __shared__ u16 Bs[64 * 32];
  int tid = threadIdx.x;
  int wave = tid >> 6, lane = tid & 63;
  int wr = wave >> 1, wc = wave & 1;
  int lm = lane & 15, lq = lane >> 4;
  int m0 = blockIdx.x * 128;

  int mLoc = tid & 127, cHalf = tid >> 7;
  int mA = m0 + mLoc;
  int bA = mA / 1444, qA = mA - bA * 1444;
  const float* aG = feat1 + ((size_t)bA * 512) * 1444 + qA;

  const u16* bG = w1b + (tid >> 2) * 512 + (tid & 3) * 8;
  char* BsW = (char*)Bs + wave * 1024;

  f32x4 acc[4][2];
#pragma unroll
  for (int i = 0; i < 4; ++i)
#pragma unroll
    for (int j = 0; j < 2; ++j)
#pragma unroll
      for (int r = 0; r < 4; ++r) acc[i][j][r] = 0.f;

  for (int k0 = 0; k0 < 512; k0 += 32) {
    gld16(bG + k0, BsW);
#pragma unroll
    for (int pass = 0; pass < 16; ++pass) {
      int c = pass * 2 + cHalf;
      As[mLoc * 40 + c] = f2bf(aG[(size_t)(k0 + c) * 1444]);
    }
    __syncthreads();
    bf16x8 aF[4], bF[2];
#pragma unroll
    for (int i = 0; i < 4; ++i)
      aF[i] = *(const bf16x8*)(As + (wr * 64 + i * 16 + lm) * 40 + lq * 8);
#pragma unroll
    for (int j = 0; j < 2; ++j)
      bF[j] = *(const bf16x8*)(Bs + (wc * 32 + j * 16 + lm) * 32 + lq * 8);
#pragma unroll
    for (int i = 0; i < 4; ++i)
#pragma unroll
      for (int j = 0; j < 2; ++j)
        acc[i][j] = __builtin_amdgcn_mfma_f32_16x16x32_bf16(aF[i], bF[j], acc[i][j], 0, 0, 0);
    __syncthreads();
  }

  int o0 = wc * 32;
  float sc[2], sh[2];
#pragma unroll
  for (int j = 0; j < 2; ++j) {
    int o = o0 + j * 16 + lm;
    sc[j] = scale1[o]; sh[j] = shift1[o];
  }
#pragma unroll
  for (int i = 0; i < 4; ++i) {
#pragma unroll
    for (int r = 0; r < 4; ++r) {
      int m = m0 + wr * 64 + i * 16 + lq * 4 + r;
      int b = m / 1444, q = m - b * 1444;
      int yy = q / 38, xx = q - yy * 38;
      size_t base = (((size_t)b * 21 + 1 + (yy >> 1)) * 21 + 1 + (xx >> 1)) * 1280
                  + ((yy & 1) * 2 + (xx & 1)) * 64;
#pragma unroll
      for (int j = 0; j < 2; ++j) {
        float v = acc[i][j][r] * sc[j] + sh[j];
        v = v > 0.f ? v : 0.1f * v;
        cat[base + o0 + j * 16 + lm] = f2bf(v);
      }
    }
  }
}

// ---------------- conv2 (3x3, 1280->1024) + BN + leaky -> pre[m][1024] bf16 ----------------
// 128x128 tile, BK=64, 4 waves (2M x 2N, per-wave 64x64), mfma_32x32x16.
// LDS 64 KiB dbuf -> 2 blocks/CU (TLP backstop). 2 barriers/K-tile, counted vmcnt(4)
// (drain only at kt=179). T2 XOR swizzle (chunk ^= row&7, 16B granule): linear gld_lds
// dest + inverse-swizzled global source + swizzled ds_read offsets (round-1-verified,
// conflicts = 0). Stage placement (race-free, barrier-separated from last reader):
//   PA(kt): vmcnt(4); BAR; stage B(kt+1)->Bs[p^1]; read aF[2][4]+bF ks01; 8 MFMA; BAR
//   PB(kt): stage A(kt+2)->As[p] (A frags already in regs); read bF ks23; 8 MFMA
__global__ __launch_bounds__(256, 2) void k_conv2(const u16* cat, const u16* w2t,
    const float* scale2, const float* shift2, u16* pre)
{
  __shared__ __align__(16) u16 As[2][8192];   // 128 rows x 64 u16 = 16 KiB per buf
  __shared__ __align__(16) u16 Bs[2][8192];

  int tid = threadIdx.x;
  int wave = tid >> 6, lane = tid & 63;
  int wr = wave >> 1, wc = wave & 1;
  int l31 = lane & 31, lh = lane >> 5, l7 = lane & 7;
  int n0 = (blockIdx.x & 7) * 128;             // XCD-affine B slice (2.95 MB L2-resident)
  int m0 = (blockIdx.x >> 3) * 128;

  // staging: thread covers row (pass*32 + tid>>3), LDS chunk tid&7; source inv-swizzled
  int rsub = tid >> 3;                         // 0..31
  int cOff = ((tid & 7) ^ (rsub & 7)) * 8;

  const u16* aBase[4];
#pragma unroll
  for (int r = 0; r < 4; ++r) {
    int m = m0 + r * 32 + rsub; if (m > 23103) m = 23103;
    int b = m / 361, pq = m - b * 361, y = pq / 19, x = pq - y * 19;
    aBase[r] = cat + ((size_t)(b * 21 + y) * 21 + x) * 1280 + cOff;
  }
  const u16* bBase[4];
#pragma unroll
  for (int r = 0; r < 4; ++r)
    bBase[r] = w2t + (size_t)(n0 + r * 32 + rsub) * 3840 + cOff;

  // read-side swizzled chunk offsets (u16 units) for k-steps 0..3
  int cks[4];
#pragma unroll
  for (int ks = 0; ks < 4; ++ks) cks[ks] = ((ks * 2 + lh) ^ l7) * 8;

  const int aRow = (wr * 64 + l31) * 64;       // u16 offset of lane's A row
  const int bRow = (wc * 64 + l31) * 64;

  f32x16 acc[2][2];
#pragma unroll
  for (int i = 0; i < 2; ++i)
#pragma unroll
    for (int j = 0; j < 2; ++j)
#pragma unroll
      for (int r = 0; r < 16; ++r) acc[i][j][r] = 0.f;

  auto stageA = [&](int p, int off) {
#pragma unroll
    for (int r = 0; r < 4; ++r)
      gld16(aBase[r] + off, &As[p][r * 2048 + wave * 512]);
  };
  auto stageB = [&](int p, size_t off) {
#pragma unroll
    for (int r = 0; r < 4; ++r)
      gld16(bBase[r] + off, &Bs[p][r * 2048 + wave * 512]);
  };

  // prologue: A(0), B(0), A(1) -> 12 in flight
  stageA(0, 0);  stageB(0, 0);  stageA(1, 64);

  int dyA = 0, koA = 128;   // K-offset state for next A stage (k-tile 2)
  int dyB = 0, koB = 64;    // for next B stage (k-tile 1)

  for (int kt = 0; kt < 180; ++kt) {
    int p = kt & 1;
    // own A(kt),B(kt) are older than the newest 4 (A(kt+1)) -> vmcnt(4) covers them
    if (kt == 179) { asm volatile("s_waitcnt vmcnt(0)" ::: "memory"); }
    else           { asm volatile("s_waitcnt vmcnt(4)" ::: "memory"); }
    __builtin_amdgcn_sched_barrier(0);
    BARX();

    // ---- PA: stage B(kt+1) (Bs[p^1] retired at tile kt-1 end, barrier-separated) ----
    if (kt < 179) {
      stageB(p ^ 1, (size_t)dyB * 3932160 + koB);
      koB += 64; if (koB == 3840) { koB = 0; ++dyB; }
    }

    const u16* Ap = &As[p][aRow];
    const u16* Bp = &Bs[p][bRow];
    bf16x8 aF[2][4], bF[2][2];
#pragma unroll
    for (int i = 0; i < 2; ++i)
#pragma unroll
      for (int ks = 0; ks < 4; ++ks)
        aF[i][ks] = *(const bf16x8*)(Ap + i * 2048 + cks[ks]);
#pragma unroll
    for (int j = 0; j < 2; ++j)
#pragma unroll
      for (int ks = 0; ks < 2; ++ks)
        bF[j][ks] = *(const bf16x8*)(Bp + j * 2048 + cks[ks]);
    LGKM0();
    __builtin_amdgcn_s_setprio(1);
#pragma unroll
    for (int ks = 0; ks < 2; ++ks)
#pragma unroll
      for (int i = 0; i < 2; ++i)
#pragma unroll
        for (int j = 0; j < 2; ++j)
          acc[i][j] = __builtin_amdgcn_mfma_f32_32x32x16_bf16(aF[i][ks], bF[j][ks], acc[i][j], 0, 0, 0);
    __builtin_amdgcn_s_setprio(0);
    BARX();   // all waves' A reads complete -> As[p] free for restage

    // ---- PB: stage A(kt+2); compute ks2,3 (A frags already in registers) ----
    if (kt < 178) {
      stageA(p, dyA * 26880 + koA);
      koA += 64; if (koA == 3840) { koA = 0; ++dyA; }
    }
#pragma unroll
    for (int j = 0; j < 2; ++j)
#pragma unroll
      for (int ks = 0; ks < 2; ++ks)
        bF[j][ks] = *(const bf16x8*)(Bp + j * 2048 + cks[2 + ks]);
    LGKM0();
    __builtin_amdgcn_s_setprio(1);
#pragma unroll
    for (int ks = 0; ks < 2; ++ks)
#pragma unroll
      for (int i = 0; i < 2; ++i)
#pragma unroll
        for (int j = 0; j < 2; ++j)
          acc[i][j] = __builtin_amdgcn_mfma_f32_32x32x16_bf16(aF[i][2 + ks], bF[j][ks], acc[i][j], 0, 0, 0);
    __builtin_amdgcn_s_setprio(0);
    // no tile-end barrier needed: next PA's restage of Bs[p^1] is after its BAR
  }

  // ---- epilogue: BN + leaky -> pre ----
  // C/D 32x32 layout: col = lane&31, row = (r&3) + 8*(r>>2) + 4*(lane>>5)
  float sc[2], sh[2];
#pragma unroll
  for (int j = 0; j < 2; ++j) {
    int n = n0 + wc * 64 + j * 32 + l31;
    sc[j] = scale2[n]; sh[j] = shift2[n];
  }
#pragma unroll
  for (int i = 0; i < 2; ++i) {
    int mb = m0 + wr * 64 + i * 32 + 4 * lh;
#pragma unroll
    for (int r = 0; r < 16; ++r) {
      int m = mb + (r & 3) + 8 * (r >> 2);
      if (m < 23104) {
        u16* row = pre + (size_t)m * 1024;
#pragma unroll
        for (int j = 0; j < 2; ++j) {
          float v = acc[i][j][r] * sc[j] + sh[j];
          v = v > 0.f ? v : 0.1f * v;
          row[n0 + wc * 64 + j * 32 + l31] = f2bf(v);
        }
      }
    }
  }
}

// ---------------- einsum: det[cw=600][pix=23104]; A=cwt(640x1024), B=pre(23104x1024) ----
__global__ __launch_bounds__(256) void k_einsum(const u16* pre, const u16* cwt,
    const float* cbf, float* out)
{
  __shared__ u16 As[4096];
  __shared__ u16 Bs[4096];
  int tid = threadIdx.x;
  int wave = tid >> 6, lane = tid & 63;
  int wr = wave >> 1, wc = wave & 1;
  int lm = lane & 15, lq = lane >> 4;
  int m0 = blockIdx.x * 128;
  int n0 = blockIdx.y * 128;

  int r0 = tid >> 2, seg = (tid & 3) * 8;
  const u16* aP0 = cwt + (size_t)(m0 + r0) * 1024 + seg;
  const u16* aP1 = aP0 + (size_t)64 * 1024;
  int q0 = n0 + r0;       if (q0 > 23103) q0 = 23103;
  int q1 = n0 + r0 + 64;  if (q1 > 23103) q1 = 23103;
  const u16* bP0 = pre + (size_t)q0 * 1024 + seg;
  const u16* bP1 = pre + (size_t)q1 * 1024 + seg;

  char* AsW = (char*)As + wave * 1024;
  char* BsW = (char*)Bs + wave * 1024;

  f32x4 acc[4][4];
#pragma unroll
  for (int i = 0; i < 4; ++i)
#pragma unroll
    for (int j = 0; j < 4; ++j)
#pragma unroll
      for (int r = 0; r < 4; ++r) acc[i][j][r] = 0.f;

  for (int k0 = 0; k0 < 1024; k0 += 32) {
    gld16(aP0 + k0, AsW);
    gld16(aP1 + k0, AsW + 4096);
    gld16(bP0 + k0, BsW);
    gld16(bP1 + k0, BsW + 4096);
    __syncthreads();
    bf16x8 aF[4], bF[4];
#pragma unroll
    for (int i = 0; i < 4; ++i)
      aF[i] = *(const bf16x8*)(As + (wr * 64 + i * 16 + lm) * 32 + lq * 8);
#pragma unroll
    for (int j = 0; j < 4; ++j)
      bF[j] = *(const bf16x8*)(Bs + (wc * 64 + j * 16 + lm) * 32 + lq * 8);
#pragma unroll
    for (int i = 0; i < 4; ++i)
#pragma unroll
      for (int j = 0; j < 4; ++j)
        acc[i][j] = __builtin_amdgcn_mfma_f32_16x16x32_bf16(aF[i], bF[j], acc[i][j], 0, 0, 0);
    __syncthreads();
  }

  int pix[4], pb[4], pp[4];
#pragma unroll
  for (int j = 0; j < 4; ++j) {
    pix[j] = n0 + wc * 64 + j * 16 + lm;
    int b = pix[j] / 361;
    pb[j] = b; pp[j] = pix[j] - b * 361;
  }
#pragma unroll
  for (int i = 0; i < 4; ++i) {
#pragma unroll
    for (int r = 0; r < 4; ++r) {
      int cw = m0 + wr * 64 + i * 16 + lq * 4 + r;
      if (cw < 600) {
        float bias = cbf[cw];
#pragma unroll
        for (int j = 0; j < 4; ++j) {
          if (pix[j] < 23104)
            out[(size_t)pb[j] * 216600 + (size_t)cw * 361 + pp[j]] = acc[i][j][r] + bias;
        }
      }
    }
  }
}

// ---------------- launch ----------------

extern "C" void kernel_launch(void* const* d_in, const int* in_sizes, int n_in,
                              void* d_out, int out_size, void* d_ws, size_t ws_size,
                              hipStream_t stream) {
  const float* feat0 = (const float*)d_in[0];
  const float* feat1 = (const float*)d_in[1];
  const float* w1 = (const float*)d_in[2];
  const float* g1 = (const float*)d_in[3];
  const float* b1 = (const float*)d_in[4];
  const float* m1 = (const float*)d_in[5];
  const float* v1 = (const float*)d_in[6];
  const float* w2 = (const float*)d_in[7];
  const float* g2 = (const float*)d_in[8];
  const float* b2 = (const float*)d_in[9];
  const float* m2 = (const float*)d_in[10];
  const float* v2 = (const float*)d_in[11];
  const float* rw = (const float*)d_in[12];
  float* out = (float*)d_out;

  char* ws = (char*)d_ws;
  u16* cat    = (u16*)(ws);                    // 72,253,440 B
  u16* w2t    = (u16*)(ws + 72253440);         // 23,592,960 B
  u16* pre    = (u16*)(ws + 95846400);         // 47,316,992 B
  u16* w1b    = (u16*)(ws + 143163392);
  u16* cwt    = (u16*)(ws + 143228928);
  float* scale1 = (float*)(ws + 144539648);
  float* shift1 = (float*)(ws + 144539904);
  float* scale2 = (float*)(ws + 144540160);
  float* shift2 = (float*)(ws + 144544256);
  float* cbf    = (float*)(ws + 144548352);

  hipMemsetAsync(cat, 0, 72253440, stream);  // zero spatial padding

  k_prep_small<<<2696, 256, 0, stream>>>(w1, rw, g1, b1, m1, v1, g2, b2, m2, v2,
                                         w1b, cwt, scale1, shift1, scale2, shift2, cbf);
  k_prep_w2<<<1024, 256, 0, stream>>>(w2, w2t);
  k_feat0<<<dim3(12, 32, 64), 256, 0, stream>>>(feat0, cat);
  k_conv1<<<722, 256, 0, stream>>>(feat1, w1b, scale1, shift1, cat);
  k_conv2<<<1448, 256, 0, stream>>>(cat, w2t, scale2, shift2, pre);
  k_einsum<<<dim3(5, 181), 256, 0, stream>>>(pre, cwt, cbf, out);
}

// Round 3
// 1189.416 us; speedup vs baseline: 1.0995x; 1.0782x over previous
//
#include <hip/hip_runtime.h>

typedef unsigned short u16;
typedef __attribute__((ext_vector_type(8))) __bf16 bf16x8;
typedef __attribute__((ext_vector_type(4))) float f32x4;

__device__ __forceinline__ u16 f2bf(float f) {
  union { float f; unsigned u; } v; v.f = f;
  unsigned r = v.u + 0x7fffu + ((v.u >> 16) & 1u);
  return (u16)(r >> 16);
}

__device__ __forceinline__ void gld16(const void* g, const void* l) {
  __builtin_amdgcn_global_load_lds((const __attribute__((address_space(1))) void*)g,
                                   (__attribute__((address_space(3))) void*)l, 16, 0, 0);
}

// ---------------- merged small prep ----------------
__global__ __launch_bounds__(256) void k_prep_small(
    const float* w1, const float* rw,
    const float* g1, const float* b1, const float* m1, const float* v1,
    const float* g2, const float* b2, const float* m2, const float* v2,
    u16* w1b, u16* cwt,
    float* scale1, float* shift1, float* scale2, float* shift2, float* cbf)
{
  int i = blockIdx.x * 256 + threadIdx.x;
  if (i < 32768) { w1b[i] = f2bf(w1[i]); return; }
  i -= 32768;
  if (i < 655360) {
    int n = i >> 10, c = i & 1023;
    cwt[i] = (n < 600) ? f2bf(rw[n * 1025 + c]) : (u16)0;
    return;
  }
  i -= 655360;
  if (i < 64) {
    float s = g1[i] * rsqrtf(v1[i] + 1e-5f);
    scale1[i] = s; shift1[i] = b1[i] - m1[i] * s;
  } else if (i < 1088) {
    int c = i - 64;
    float s = g2[c] * rsqrtf(v2[c] + 1e-5f);
    scale2[c] = s; shift2[c] = b2[c] - m2[c] * s;
  } else if (i < 1728) {
    int n = i - 1088;
    cbf[n] = (n < 600) ? rw[n * 1025 + 1024] : 0.f;
  }
}

// w2 (1024,1280,3,3) OIHW -> w2t[dy][o][dx*1280+ci] bf16
__global__ __launch_bounds__(256) void k_prep_w2(const float* w2, u16* w2t) {
  __shared__ float buf[11520];
  int o = blockIdx.x;
  const float* src = w2 + (size_t)o * 11520;
  for (int i = threadIdx.x; i < 11520; i += 256) buf[i] = src[i];
  __syncthreads();
  for (int t = 0; t < 9; ++t) {
    int dy = t / 3, dx = t - dy * 3;
    u16* dst = w2t + ((size_t)dy * 1024 + o) * 3840 + dx * 1280;
    for (int ci = threadIdx.x; ci < 1280; ci += 256) dst[ci] = f2bf(buf[ci * 9 + t]);
  }
}

// feat0 NCHW (64,1024,19,19) -> cat[b][1+h][1+w][256+c] bf16 (NHWC, padded 21x21)
__global__ __launch_bounds__(256) void k_feat0(const float* feat0, u16* cat) {
  __shared__ float tile[32][33];
  int b = blockIdx.z, c0 = blockIdx.y * 32, p0 = blockIdx.x * 32;
  int tid = threadIdx.x;
  int lo = tid & 31, hi = tid >> 5;
#pragma unroll
  for (int pass = 0; pass < 4; ++pass) {
    int cl = pass * 8 + hi;
    int p = p0 + lo;
    tile[cl][lo] = (p < 361) ? feat0[((size_t)(b * 1024 + c0 + cl)) * 361 + p] : 0.f;
  }
  __syncthreads();
#pragma unroll
  for (int pass = 0; pass < 4; ++pass) {
    int pl = pass * 8 + hi;
    int p = p0 + pl;
    if (p < 361) {
      int h = p / 19, w = p - h * 19;
      cat[(((size_t)b * 21 + 1 + h) * 21 + 1 + w) * 1280 + 256 + c0 + lo] = f2bf(tile[lo][pl]);
    }
  }
}

// ---------------- conv1 (1x1, 512->64) + BN + leaky + reorg -> cat ch 0..255 ----------------
// Bs (64x32 u16 rows): XOR-swizzled chunk' = chunk ^ ((row>>1)&3) to break the 8-way
// conflict (64-B rows put 16 lanes on 2 bank-groups). Source pre-swizzled, dest linear.
__global__ __launch_bounds__(256) void k_conv1(const float* feat1, const u16* w1b,
    const float* scale1, const float* shift1, u16* cat)
{
  __shared__ u16 As[128 * 40];
  __shared__ u16 Bs[64 * 32];
  int tid = threadIdx.x;
  int wave = tid >> 6, lane = tid & 63;
  int wr = wave >> 1, wc = wave & 1;
  int lm = lane & 15, lq = lane >> 4;
  int csw = (lq ^ ((lm >> 1) & 3)) * 8;   // swizzled read chunk (u16 units)
  int m0 = blockIdx.x * 128;

  int mLoc = tid & 127, cHalf = tid >> 7;
  int mA = m0 + mLoc;
  int bA = mA / 1444, qA = mA - bA * 1444;
  const float* aG = feat1 + ((size_t)bA * 512) * 1444 + qA;

  // staging row = wave*16 + (lane>>2); (row>>1)&3 = (lane>>3)&3 -> inverse-swizzle source
  const u16* bG = w1b + (tid >> 2) * 512 + (((tid & 3) ^ ((tid >> 3) & 3)) * 8);
  char* BsW = (char*)Bs + wave * 1024;

  f32x4 acc[4][2];
#pragma unroll
  for (int i = 0; i < 4; ++i)
#pragma unroll
    for (int j = 0; j < 2; ++j)
#pragma unroll
      for (int r = 0; r < 4; ++r) acc[i][j][r] = 0.f;

  for (int k0 = 0; k0 < 512; k0 += 32) {
    gld16(bG + k0, BsW);
#pragma unroll
    for (int pass = 0; pass < 16; ++pass) {
      int c = pass * 2 + cHalf;
      As[mLoc * 40 + c] = f2bf(aG[(size_t)(k0 + c) * 1444]);
    }
    __syncthreads();
    bf16x8 aF[4], bF[2];
#pragma unroll
    for (int i = 0; i < 4; ++i)
      aF[i] = *(const bf16x8*)(As + (wr * 64 + i * 16 + lm) * 40 + lq * 8);
#pragma unroll
    for (int j = 0; j < 2; ++j)
      bF[j] = *(const bf16x8*)(Bs + (wc * 32 + j * 16 + lm) * 32 + csw);
#pragma unroll
    for (int i = 0; i < 4; ++i)
#pragma unroll
      for (int j = 0; j < 2; ++j)
        acc[i][j] = __builtin_amdgcn_mfma_f32_16x16x32_bf16(aF[i], bF[j], acc[i][j], 0, 0, 0);
    __syncthreads();
  }

  int o0 = wc * 32;
  float sc[2], sh[2];
#pragma unroll
  for (int j = 0; j < 2; ++j) {
    int o = o0 + j * 16 + lm;
    sc[j] = scale1[o]; sh[j] = shift1[o];
  }
#pragma unroll
  for (int i = 0; i < 4; ++i) {
#pragma unroll
    for (int r = 0; r < 4; ++r) {
      int m = m0 + wr * 64 + i * 16 + lq * 4 + r;
      int b = m / 1444, q = m - b * 1444;
      int yy = q / 38, xx = q - yy * 38;
      size_t base = (((size_t)b * 21 + 1 + (yy >> 1)) * 21 + 1 + (xx >> 1)) * 1280
                  + ((yy & 1) * 2 + (xx & 1)) * 64;
#pragma unroll
      for (int j = 0; j < 2; ++j) {
        float v = acc[i][j][r] * sc[j] + sh[j];
        v = v > 0.f ? v : 0.1f * v;
        cat[base + o0 + j * 16 + lm] = f2bf(v);
      }
    }
  }
}

// ---------------- conv2 (3x3, 1280->1024) + BN + leaky -> pre[m][1024] bf16 ----------------
// Round-0 structure (verified fastest): implicit GEMM, BK=64 (two 32-K panels),
// n0 = bid&7 XCD-affinity. NEW: XOR swizzle chunk' = chunk ^ ((row>>1)&3) on the
// 64-B-row LDS tiles (kills the measured 6.7e7 8-way conflict cycles). Both-sides:
// staging source offset inverse-swizzled (row = wave*16 + lane>>2 -> (lane>>3)&3),
// gld_lds dest linear, ds_read chunk swizzled (read row = .. + lm -> (lm>>1)&3).
__global__ __launch_bounds__(256) void k_conv2(const u16* cat, const u16* w2t,
    const float* scale2, const float* shift2, u16* pre)
{
  __shared__ u16 As[8192];
  __shared__ u16 Bs[8192];
  int tid = threadIdx.x;
  int wave = tid >> 6, lane = tid & 63;
  int wr = wave >> 1, wc = wave & 1;
  int lm = lane & 15, lq = lane >> 4;
  int csw = (lq ^ ((lm >> 1) & 3)) * 8;   // swizzled read chunk
  int n0 = (blockIdx.x & 7) * 128;
  int m0 = (blockIdx.x >> 3) * 128;

  int rIn = lane >> 2;
  int kseg = (((lane & 3) ^ ((lane >> 3) & 3)) * 8);  // inverse-swizzled source chunk
  int rowLo = wave * 16 + rIn;

  int mLo = m0 + rowLo;       if (mLo > 23103) mLo = 23103;
  int mHi = m0 + rowLo + 64;  if (mHi > 23103) mHi = 23103;
  int bL = mLo / 361, pL = mLo - bL * 361, yL = pL / 19, xL = pL - yL * 19;
  int bH = mHi / 361, pH = mHi - bH * 361, yH = pH / 19, xH = pH - yH * 19;
  const u16* aLo = cat + ((size_t)(bL * 21 + yL) * 21 + xL) * 1280 + kseg;
  const u16* aHi = cat + ((size_t)(bH * 21 + yH) * 21 + xH) * 1280 + kseg;
  const u16* bLo = w2t + (size_t)(n0 + rowLo) * 3840 + kseg;
  const u16* bHi = bLo + (size_t)64 * 3840;

  u16* asJ0 = As + wave * 512;          u16* asJ1 = As + (4 + wave) * 512;
  u16* asJ2 = As + 4096 + wave * 512;   u16* asJ3 = As + 4096 + (4 + wave) * 512;
  u16* bsJ0 = Bs + wave * 512;          u16* bsJ1 = Bs + (4 + wave) * 512;
  u16* bsJ2 = Bs + 4096 + wave * 512;   u16* bsJ3 = Bs + 4096 + (4 + wave) * 512;

  f32x4 acc[4][4];
#pragma unroll
  for (int i = 0; i < 4; ++i)
#pragma unroll
    for (int j = 0; j < 4; ++j)
#pragma unroll
      for (int r = 0; r < 4; ++r) acc[i][j][r] = 0.f;

  for (int dy = 0; dy < 3; ++dy) {
    const u16* a0 = aLo + dy * 26880;
    const u16* a1 = aHi + dy * 26880;
    const u16* b0 = bLo + (size_t)dy * 3932160;
    const u16* b1 = bHi + (size_t)dy * 3932160;
    for (int k0 = 0; k0 < 3840; k0 += 64) {
      gld16(a0 + k0,      asJ0);
      gld16(a1 + k0,      asJ1);
      gld16(a0 + k0 + 32, asJ2);
      gld16(a1 + k0 + 32, asJ3);
      gld16(b0 + k0,      bsJ0);
      gld16(b1 + k0,      bsJ1);
      gld16(b0 + k0 + 32, bsJ2);
      gld16(b1 + k0 + 32, bsJ3);
      __syncthreads();
#pragma unroll
      for (int kk = 0; kk < 2; ++kk) {
        bf16x8 aF[4], bF[4];
#pragma unroll
        for (int i = 0; i < 4; ++i)
          aF[i] = *(const bf16x8*)(As + kk * 4096 + (wr * 64 + i * 16 + lm) * 32 + csw);
#pragma unroll
        for (int j = 0; j < 4; ++j)
          bF[j] = *(const bf16x8*)(Bs + kk * 4096 + (wc * 64 + j * 16 + lm) * 32 + csw);
#pragma unroll
        for (int i = 0; i < 4; ++i)
#pragma unroll
          for (int j = 0; j < 4; ++j)
            acc[i][j] = __builtin_amdgcn_mfma_f32_16x16x32_bf16(aF[i], bF[j], acc[i][j], 0, 0, 0);
      }
      __syncthreads();
    }
  }

  int nn[4]; float sc[4], sh[4];
#pragma unroll
  for (int j = 0; j < 4; ++j) {
    nn[j] = n0 + wc * 64 + j * 16 + lm;
    sc[j] = scale2[nn[j]]; sh[j] = shift2[nn[j]];
  }
#pragma unroll
  for (int i = 0; i < 4; ++i) {
#pragma unroll
    for (int r = 0; r < 4; ++r) {
      int m = m0 + wr * 64 + i * 16 + lq * 4 + r;
      if (m < 23104) {
        u16* row = pre + (size_t)m * 1024;
#pragma unroll
        for (int j = 0; j < 4; ++j) {
          float v = acc[i][j][r] * sc[j] + sh[j];
          v = v > 0.f ? v : 0.1f * v;
          row[nn[j]] = f2bf(v);
        }
      }
    }
  }
}

// ---------------- einsum: det[cw=600][pix=23104]; A=cwt(640x1024), B=pre(23104x1024) ----
// Same XOR swizzle applied (identical 64-B-row LDS geometry).
__global__ __launch_bounds__(256) void k_einsum(const u16* pre, const u16* cwt,
    const float* cbf, float* out)
{
  __shared__ u16 As[4096];
  __shared__ u16 Bs[4096];
  int tid = threadIdx.x;
  int wave = tid >> 6, lane = tid & 63;
  int wr = wave >> 1, wc = wave & 1;
  int lm = lane & 15, lq = lane >> 4;
  int csw = (lq ^ ((lm >> 1) & 3)) * 8;
  int m0 = blockIdx.x * 128;
  int n0 = blockIdx.y * 128;

  int r0 = tid >> 2;
  int seg = (((tid & 3) ^ ((tid >> 3) & 3)) * 8);   // inverse-swizzled source chunk
  const u16* aP0 = cwt + (size_t)(m0 + r0) * 1024 + seg;
  const u16* aP1 = aP0 + (size_t)64 * 1024;
  int q0 = n0 + r0;       if (q0 > 23103) q0 = 23103;
  int q1 = n0 + r0 + 64;  if (q1 > 23103) q1 = 23103;
  const u16* bP0 = pre + (size_t)q0 * 1024 + seg;
  const u16* bP1 = pre + (size_t)q1 * 1024 + seg;

  char* AsW = (char*)As + wave * 1024;
  char* BsW = (char*)Bs + wave * 1024;

  f32x4 acc[4][4];
#pragma unroll
  for (int i = 0; i < 4; ++i)
#pragma unroll
    for (int j = 0; j < 4; ++j)
#pragma unroll
      for (int r = 0; r < 4; ++r) acc[i][j][r] = 0.f;

  for (int k0 = 0; k0 < 1024; k0 += 32) {
    gld16(aP0 + k0, AsW);
    gld16(aP1 + k0, AsW + 4096);
    gld16(bP0 + k0, BsW);
    gld16(bP1 + k0, BsW + 4096);
    __syncthreads();
    bf16x8 aF[4], bF[4];
#pragma unroll
    for (int i = 0; i < 4; ++i)
      aF[i] = *(const bf16x8*)(As + (wr * 64 + i * 16 + lm) * 32 + csw);
#pragma unroll
    for (int j = 0; j < 4; ++j)
      bF[j] = *(const bf16x8*)(Bs + (wc * 64 + j * 16 + lm) * 32 + csw);
#pragma unroll
    for (int i = 0; i < 4; ++i)
#pragma unroll
      for (int j = 0; j < 4; ++j)
        acc[i][j] = __builtin_amdgcn_mfma_f32_16x16x32_bf16(aF[i], bF[j], acc[i][j], 0, 0, 0);
    __syncthreads();
  }

  int pix[4], pb[4], pp[4];
#pragma unroll
  for (int j = 0; j < 4; ++j) {
    pix[j] = n0 + wc * 64 + j * 16 + lm;
    int b = pix[j] / 361;
    pb[j] = b; pp[j] = pix[j] - b * 361;
  }
#pragma unroll
  for (int i = 0; i < 4; ++i) {
#pragma unroll
    for (int r = 0; r < 4; ++r) {
      int cw = m0 + wr * 64 + i * 16 + lq * 4 + r;
      if (cw < 600) {
        float bias = cbf[cw];
#pragma unroll
        for (int j = 0; j < 4; ++j) {
          if (pix[j] < 23104)
            out[(size_t)pb[j] * 216600 + (size_t)cw * 361 + pp[j]] = acc[i][j][r] + bias;
        }
      }
    }
  }
}

// ---------------- launch ----------------

extern "C" void kernel_launch(void* const* d_in, const int* in_sizes, int n_in,
                              void* d_out, int out_size, void* d_ws, size_t ws_size,
                              hipStream_t stream) {
  const float* feat0 = (const float*)d_in[0];
  const float* feat1 = (const float*)d_in[1];
  const float* w1 = (const float*)d_in[2];
  const float* g1 = (const float*)d_in[3];
  const float* b1 = (const float*)d_in[4];
  const float* m1 = (const float*)d_in[5];
  const float* v1 = (const float*)d_in[6];
  const float* w2 = (const float*)d_in[7];
  const float* g2 = (const float*)d_in[8];
  const float* b2 = (const float*)d_in[9];
  const float* m2 = (const float*)d_in[10];
  const float* v2 = (const float*)d_in[11];
  const float* rw = (const float*)d_in[12];
  float* out = (float*)d_out;

  char* ws = (char*)d_ws;
  u16* cat    = (u16*)(ws);                    // 72,253,440 B
  u16* w2t    = (u16*)(ws + 72253440);         // 23,592,960 B
  u16* pre    = (u16*)(ws + 95846400);         // 47,316,992 B
  u16* w1b    = (u16*)(ws + 143163392);
  u16* cwt    = (u16*)(ws + 143228928);
  float* scale1 = (float*)(ws + 144539648);
  float* shift1 = (float*)(ws + 144539904);
  float* scale2 = (float*)(ws + 144540160);
  float* shift2 = (float*)(ws + 144544256);
  float* cbf    = (float*)(ws + 144548352);

  hipMemsetAsync(cat, 0, 72253440, stream);  // zero spatial padding

  k_prep_small<<<2696, 256, 0, stream>>>(w1, rw, g1, b1, m1, v1, g2, b2, m2, v2,
                                         w1b, cwt, scale1, shift1, scale2, shift2, cbf);
  k_prep_w2<<<1024, 256, 0, stream>>>(w2, w2t);
  k_feat0<<<dim3(12, 32, 64), 256, 0, stream>>>(feat0, cat);
  k_conv1<<<722, 256, 0, stream>>>(feat1, w1b, scale1, shift1, cat);
  k_conv2<<<1448, 256, 0, stream>>>(cat, w2t, scale2, shift2, pre);
  k_einsum<<<dim3(5, 181), 256, 0, stream>>>(pre, cwt, cbf, out);
}